// Round 8
// baseline (162.828 us; speedup 1.0000x reference)
//
#include <hip/hip_runtime.h>

#define NN 6144
#define DD 768
#define INV_T 14.285714285714286f
#define CMAX  14.285714285714286f

// 64x64 wave-tiles over the upper triangle: 96x97/2 = 4656 tiles.
// Supertiles of 24x24 tiles (4x4 grid): diag 300, offdiag 576;
// row sizes 2028/1452/876/300; total 4656 = 8 * 582 exactly.
#define NWT 582              // wave-tiles per XCD chunk

typedef int i32x4 __attribute__((ext_vector_type(4)));
typedef int i32x8 __attribute__((ext_vector_type(8)));
typedef float f32x16 __attribute__((ext_vector_type(16)));

__device__ __forceinline__ i32x8 ld32B(const unsigned char* p) {
    i32x4 lo = *(const i32x4*)p;
    i32x4 hi = *(const i32x4*)(p + 16);
    return __builtin_shufflevector(lo, hi, 0, 1, 2, 3, 4, 5, 6, 7);
}

// Kernel 1: L2-normalize rows -> fp8 e4m3 (unit MX scale); zero den/num sums.
// One wave per row; 1536 blocks x 256 threads.
__global__ void norm_kernel(const float* __restrict__ feats,
                            unsigned int* __restrict__ fb8,   // 6144*192 uints
                            float* __restrict__ den_num) {    // [0..NN)=den, [NN..2NN)=num
    const int wid = threadIdx.x >> 6;
    const int lane = threadIdx.x & 63;
    const int row = blockIdx.x * 4 + wid;

    if (threadIdx.x < 8) den_num[blockIdx.x * 8 + threadIdx.x] = 0.0f;

    const float4* src = (const float4*)(feats + (size_t)row * DD);
    float4 v[3];
    float ss = 0.0f;
#pragma unroll
    for (int i = 0; i < 3; ++i) {
        v[i] = src[lane + i * 64];
        ss += v[i].x * v[i].x + v[i].y * v[i].y + v[i].z * v[i].z + v[i].w * v[i].w;
    }
#pragma unroll
    for (int m = 32; m >= 1; m >>= 1) ss += __shfl_xor(ss, m);
    const float sc = 1.0f / fmaxf(sqrtf(ss), 1e-12f);

#pragma unroll
    for (int i = 0; i < 3; ++i) {
        unsigned int w = 0;
        w = __builtin_amdgcn_cvt_pk_fp8_f32(v[i].x * sc, v[i].y * sc, w, 0);
        w = __builtin_amdgcn_cvt_pk_fp8_f32(v[i].z * sc, v[i].w * sc, w, 1);
        fb8[(size_t)row * 192 + lane + i * 64] = w;
    }
}

// Kernel 2 (r13): ZERO-BARRIER, ZERO-LDS Gram + fused exp sums.
//
// Post-mortem of r6..r12: every variant of the barriered-LDS structure
// (single buf 55us, dbuf 55us, counted-vmcnt 44-50us, 8-wave 80us) sits at
// MfmaUtil<10% with all pipes idle. Per-CU accounting: our blocks carry
// only 1.4us of CU-MFMA work but cost 15-24us: with K=768 there are only
// 6 K-steps, so the per-barrier-step fixed stall can never amortize
// (guide's m97 works because its blocks have 64 steps / 16.5us MFMA).
// The structure was wrong for this shape, not mis-tuned.
//
// r13 deletes the mechanism class: fb8 (4.7 MB) is L2-resident, so each
// wave computes one 64x64 output tile with MFMA fragments loaded DIRECTLY
// from global (L2) into registers. No LDS, no barriers, no global_load_lds,
// no bank conflicts. 4656 fully independent waves; latency hidden by TLP
// (no LDS -> VGPR-limited occupancy, ~12 waves/CU, launch_bounds(256,3)
// caps VGPR at ~170 -- r11 lesson: never cap below need).
// 32x32x64 MX-fp8 MFMA: fragment loads read full 64B lines (rows 64B-
// aligned; lanes 0-31 chunk k..k+31, lanes 32-63 chunk k+32..k+63 of the
// same lines) -> zero over-fetch. L2 traffic 4656 x 96KB = 447 MB ~= 13us
// at aggregate L2 BW; MFMA floor 6.3us overlaps. Supertile XCD chunking
// kept (24x24-tile supertiles, 4656 = 8*582 exact, ~2.4MB/chunk fits L2).
__global__ __launch_bounds__(256, 3) void gemm_expsum_kernel(
        const unsigned char* __restrict__ fb8,
        float* __restrict__ den_sum, float* __restrict__ num_sum) {
    const int wid = threadIdx.x >> 6;
    const int lane = threadIdx.x & 63;

    // wave-tile id: XCD chunk = blockIdx&7 (dispatch round-robin), 4 waves
    // per block, 146 blocks per chunk cover 582 tiles (last block ragged).
    const int chunk = blockIdx.x & 7;
    const int pos = blockIdx.x >> 3;
    const int qq = pos * 4 + wid;
    if (qq >= NWT) return;
    int rem = chunk * NWT + qq;      // position in supertile-ordered list

    // ---- arithmetic decode: supertile-ordered index -> (ti, tj), ti<=tj
    int si = 0;
    while (rem >= 2028 - 576 * si) { rem -= 2028 - 576 * si; ++si; }
    int ti, tj;
    if (rem < 300) {                 // diagonal supertile: 24x24 triangle
        int r = 0;
        while (rem >= 24 - r) { rem -= 24 - r; ++r; }
        ti = si * 24 + r;
        tj = si * 24 + r + rem;
    } else {                         // off-diagonal supertiles, 576 each
        rem -= 300;
        const int sj = si + 1 + rem / 576;
        const int lo = rem % 576;
        ti = si * 24 + lo / 24;
        tj = sj * 24 + lo % 24;
    }
    const bool isdiag = (ti == tj);
    const bool neardiag = (tj - ti) <= 1;
    const int i0 = ti * 64;
    const int j0 = tj * 64;

    const int l31 = lane & 31;
    const int hi = lane >> 5;        // k-chunk group for A/B frags

    // Fragment bases: A row i0+mi*32+l31, B row j0+ni*32+l31; lane group hi
    // covers k-bytes [hi*32, hi*32+32) of each 64-wide K step.
    const unsigned char* pa0 = fb8 + (size_t)(i0 + l31) * DD + hi * 32;
    const unsigned char* pa1 = pa0 + (size_t)32 * DD;
    const unsigned char* pb0 = fb8 + (size_t)(j0 + l31) * DD + hi * 32;
    const unsigned char* pb1 = pb0 + (size_t)32 * DD;

    f32x16 acc[2][2];
    const f32x16 z16 = {0.f,0.f,0.f,0.f,0.f,0.f,0.f,0.f,
                        0.f,0.f,0.f,0.f,0.f,0.f,0.f,0.f};
    acc[0][0] = z16; acc[0][1] = z16; acc[1][0] = z16; acc[1][1] = z16;

    // K-loop: 12 steps of K=64. Per step: 8 dwordx4 loads + 4 MFMA.
    // Rolled (#pragma unroll 1): r2/r7 lesson — full unroll spills.
    // Per-step L2 latency is absorbed by 12 independent waves/CU.
#pragma unroll 1
    for (int s = 0; s < 12; ++s) {
        const int k0 = s * 64;
        i32x8 a0 = ld32B(pa0 + k0);
        i32x8 a1 = ld32B(pa1 + k0);
        i32x8 b0 = ld32B(pb0 + k0);
        i32x8 b1 = ld32B(pb1 + k0);
        acc[0][0] = __builtin_amdgcn_mfma_scale_f32_32x32x64_f8f6f4(
            a0, b0, acc[0][0], 0, 0, 0, 0x7F7F7F7F, 0, 0x7F7F7F7F);
        acc[0][1] = __builtin_amdgcn_mfma_scale_f32_32x32x64_f8f6f4(
            a0, b1, acc[0][1], 0, 0, 0, 0x7F7F7F7F, 0, 0x7F7F7F7F);
        acc[1][0] = __builtin_amdgcn_mfma_scale_f32_32x32x64_f8f6f4(
            a1, b0, acc[1][0], 0, 0, 0, 0x7F7F7F7F, 0, 0x7F7F7F7F);
        acc[1][1] = __builtin_amdgcn_mfma_scale_f32_32x32x64_f8f6f4(
            a1, b1, acc[1][1], 0, 0, 0, 0x7F7F7F7F, 0, 0x7F7F7F7F);
    }

    // Epilogue. 32x32 C/D layout: col = lane&31 (+ni*32),
    // row = (reg&3) + 8*(reg>>2) + 4*hi (+mi*32).  [guide §3, shape-det.]
    float colp0 = 0.f, colp1 = 0.f, coln0 = 0.f, coln1 = 0.f;
#pragma unroll
    for (int mi = 0; mi < 2; ++mi) {
#pragma unroll
        for (int reg = 0; reg < 16; ++reg) {
            const int row = i0 + mi * 32 + (reg & 3) + 8 * (reg >> 2) + 4 * hi;
            const int c0 = j0 + l31;
            const int c1 = j0 + 32 + l31;
            float e0 = __expf(__builtin_fmaf(acc[mi][0][reg], INV_T, -CMAX));
            float e1 = __expf(__builtin_fmaf(acc[mi][1][reg], INV_T, -CMAX));
            if (isdiag && row == c0) e0 = 0.0f;
            if (isdiag && row == c1) e1 = 0.0f;

            // row sum across the 32 cols held by this 32-lane half
            float rv = e0 + e1;
            rv += __shfl_xor(rv, 16);
            rv += __shfl_xor(rv, 8);
            rv += __shfl_xor(rv, 4);
            rv += __shfl_xor(rv, 2);
            rv += __shfl_xor(rv, 1);
            if (l31 == 0) atomicAdd(&den_sum[row], rv);

            colp0 += e0;
            colp1 += e1;

            if (neardiag) {
                float n0 = (row != c0 && (row / 3) == (c0 / 3)) ? e0 : 0.0f;
                float n1 = (row != c1 && (row / 3) == (c1 / 3)) ? e1 : 0.0f;
                float rn = n0 + n1;
                rn += __shfl_xor(rn, 16);
                rn += __shfl_xor(rn, 8);
                rn += __shfl_xor(rn, 4);
                rn += __shfl_xor(rn, 2);
                rn += __shfl_xor(rn, 1);
                if (l31 == 0) atomicAdd(&num_sum[row], rn);
                coln0 += n0;
                coln1 += n1;
            }
        }
    }
    // column sums: add the other half's 32 rows, then one atomic per col.
    // Diag tiles skip cols (full-square tile: row sums already count all).
    if (!isdiag) {
        colp0 += __shfl_xor(colp0, 32);
        colp1 += __shfl_xor(colp1, 32);
        if (hi == 0) {
            atomicAdd(&den_sum[j0 + l31], colp0);
            atomicAdd(&den_sum[j0 + 32 + l31], colp1);
        }
        if (neardiag) {
            coln0 += __shfl_xor(coln0, 32);
            coln1 += __shfl_xor(coln1, 32);
            if (hi == 0) {
                atomicAdd(&num_sum[j0 + l31], coln0);
                atomicAdd(&num_sum[j0 + 32 + l31], coln1);
            }
        }
    }
}

// Kernel 3: loss = mean(log(den) - log(num))  (CMAX cancels). Single block.
__global__ void finalize_kernel(const float* __restrict__ den_sum,
                                const float* __restrict__ num_sum,
                                float* __restrict__ out) {
    float local = 0.0f;
    for (int i = threadIdx.x; i < NN; i += 256) {
        local += logf(den_sum[i]) - logf(num_sum[i]);
    }
#pragma unroll
    for (int m = 32; m >= 1; m >>= 1) local += __shfl_xor(local, m);
    __shared__ float ws[4];
    if ((threadIdx.x & 63) == 0) ws[threadIdx.x >> 6] = local;
    __syncthreads();
    if (threadIdx.x == 0) out[0] = (ws[0] + ws[1] + ws[2] + ws[3]) / (float)NN;
}

extern "C" void kernel_launch(void* const* d_in, const int* in_sizes, int n_in,
                              void* d_out, int out_size, void* d_ws, size_t ws_size,
                              hipStream_t stream) {
    const float* feats = (const float*)d_in[0];
    float* out = (float*)d_out;

    char* ws = (char*)d_ws;
    unsigned int* fb8 = (unsigned int*)ws;                 // 6144*768 = 4718592 B
    float* den_num    = (float*)(ws + 4718592);            // 2*6144*4 B
    float* den_sum    = den_num;
    float* num_sum    = den_num + NN;

    norm_kernel<<<NN / 4, 256, 0, stream>>>(feats, fb8, den_num);
    // 8 XCD chunks x 146 blocks x 4 waves covers 8 x 582 wave-tiles
    gemm_expsum_kernel<<<8 * 146, 256, 0, stream>>>((const unsigned char*)fb8,
                                                    den_sum, num_sum);
    finalize_kernel<<<1, 256, 0, stream>>>(den_sum, num_sum, out);
}